// Round 12
// baseline (4354.616 us; speedup 1.0000x reference)
//
#include <hip/hip_runtime.h>
#include <math.h>

// BarrierNet fused kernel, fp32, round 12 = round 11 resubmitted verbatim
// (round 11 never ran: GPU acquisition timeout).
// Round-10 result: 976us, VALUBusy 65%, Occupancy 57%, VGPR 40 (pass, absmax
// 0.5). Remaining 35% idle = wave-uniform s_load weight stream (128B/64cyc
// k-step, K$-miss ~200cyc) insufficiently hidden. MFMA rejected: delta_out ~
// delta_h/|G| amplification (np-jax 0.58 @ 1e-7 perturbation) makes bf16-level
// network error blow the 4.66 threshold -> fp32 VALU is structural.
// This round: 64 cols/wave (256-thr blocks, 4 waves) -> 64 FMA (128cyc) per
// 256B s_load batch: stall-per-FMA halved, recompute overhead halved, FMA
// density 91%. Per-col accumulation order unchanged -> bit-identical output.
//   block = 256 thr (4 waves), 64 rows (lane=row), wave owns 64 cols of
//   concat(h21,h22); 16 chunks x 32 k.

#define NBATCH 262144
#define MT 64
#define NTHREADS 256
#define WCOLS 64    // cols per wave
#define CHUNK 32
#define NCHUNK 16   // 512 / CHUNK

__global__ void transpose_w_kernel(const float* __restrict__ W21,
                                   const float* __restrict__ W22,
                                   float* __restrict__ Wt) {
    int idx = blockIdx.x * blockDim.x + threadIdx.x;  // 0..131071
    if (idx >= 512 * 256) return;
    int k = idx >> 8;    // 0..511
    int c = idx & 255;   // 0..255
    float v = (c < 128) ? W21[c * 512 + k] : W22[(c - 128) * 512 + k];
    Wt[idx] = v;         // Wt[k][c]
}

__global__ __launch_bounds__(NTHREADS, 5)
void barriernet_kernel(const float* __restrict__ x,
                       const float* __restrict__ W1,  const float* __restrict__ b1,
                       const float* __restrict__ b21, const float* __restrict__ b22,
                       const float* __restrict__ W31, const float* __restrict__ b31,
                       const float* __restrict__ W32, const float* __restrict__ b32,
                       const float* __restrict__ Wt,
                       float* __restrict__ out) {
    __shared__ float red[4][MT][2];      // layer-3 partials per wave (2 KiB)

    const int t    = threadIdx.x;
    const int lane = t & 63;             // = row within block
    const int wv   = __builtin_amdgcn_readfirstlane(t >> 6);  // 0..3 wave-uniform
    const int row0 = blockIdx.x * MT;

    // ---- per-lane raw x (row = lane), one coalesced 16B load ----
    const float4 xi = reinterpret_cast<const float4*>(x)[row0 + lane];
    const float a0 = xi.x, a1 = xi.y, a2 = xi.z, a3 = xi.w;

    // ---- fused recompute-h1 + GEMM over 16 chunks of 32 k ----
    const int cbase = wv * WCOLS;        // wave-uniform col base (0/64/128/192)
    float acc[WCOLS];
    #pragma unroll
    for (int j = 0; j < WCOLS; ++j) acc[j] = 0.f;

    for (int c = 0; c < NCHUNK; ++c) {   // real loop: keep body in I-cache
        #pragma unroll
        for (int kk = 0; kk < CHUNK; ++kk) {
            const int k = c * CHUNK + kk;
            // recompute activation for this k (uniform W1/b1 -> s_load)
            const float* w1k = W1 + k * 4;
            float v = b1[k];
            v = fmaf(a0, w1k[0], v);
            v = fmaf(a1, w1k[1], v);
            v = fmaf(a2, w1k[2], v);
            v = fmaf(a3, w1k[3], v);
            const float act = fmaxf(v, 0.f);
            // 64 FMAs: uniform weight stream, register activation
            const float* wk = Wt + k * 256 + cbase;  // wave-uniform
            #pragma unroll
            for (int j = 0; j < WCOLS; ++j) acc[j] = fmaf(act, wk[j], acc[j]);
        }
    }

    // ---- bias + relu + partial dots with W31/W32 (layer 3) ----
    // wave 0: h21 cols 0-63, wave 1: h21 64-127, wave 2: h22 0-63, wave 3: h22 64-127
    {
        const bool isA  = (wv < 2);
        const int  coff = isA ? (wv * WCOLS) : ((wv - 2) * WCOLS);
        const float* bb = isA ? b21 : b22;
        const float* W3 = isA ? W31 : W32;               // (2,128) row-major
        float q0 = 0.f, q1 = 0.f;
        #pragma unroll
        for (int j = 0; j < WCOLS; ++j) {
            float hv = fmaxf(acc[j] + bb[coff + j], 0.f);
            q0 = fmaf(hv, W3[coff + j], q0);
            q1 = fmaf(hv, W3[128 + coff + j], q1);
        }
        red[wv][lane][0] = q0;
        red[wv][lane][1] = q1;
    }
    __syncthreads();

    // ---- epilogue: CBF-QP closed form (wave 0, one lane per row, fp64) ----
    if (t < MT) {
        const int r = t;                 // lane==row, wave 0 -> own x regs valid
        float x31_0f = b31[0], x31_1f = b31[1];
        float z0f = b32[0], z1f = b32[1];
        x31_0f += red[0][r][0] + red[1][r][0];
        x31_1f += red[0][r][1] + red[1][r][1];
        z0f    += red[2][r][0] + red[3][r][0];
        z1f    += red[2][r][1] + red[3][r][1];

        const double s0 = 4.0 / (1.0 + exp(-(double)z0f));
        const double s1 = 4.0 / (1.0 + exp(-(double)z1f));

        // un-normalize raw x for the physics: STD={10,10,1,2}, MEAN={50,20,0,5}
        const double px = (double)a0 * 10.0 + 50.0;
        const double py = (double)a1 * 10.0 + 20.0;
        const double th = (double)a2;
        const double v  = (double)a3 * 2.0 + 5.0;

        const double st = sin(th), ct = cos(th);
        const double dx = px - 40.0, dy = py - 15.0;
        const double barrier     = dx * dx + dy * dy - 36.0;
        const double barrier_dot = 2.0 * dx * v * ct + 2.0 * dy * v * st;
        const double Lf2b        = 2.0 * v * v;
        const double LgLfbu1     = -2.0 * dx * v * st + 2.0 * dy * v * ct;
        const double LgLfbu2     = 2.0 * dx * ct + 2.0 * dy * st;
        const double G0 = -LgLfbu1, G1 = -LgLfbu2;
        const double h  = Lf2b + (s0 + s1) * barrier_dot + s0 * s1 * barrier;
        const double u0 = -(double)x31_0f, u1 = -(double)x31_1f;
        const double Gu = G0 * u0 + G1 * u1;
        const double gg = fmax(G0 * G0 + G1 * G1, 1e-12);
        const double lam = fmax(0.0, (Gu - h) / gg);
        float2 o;
        o.x = (float)(u0 - lam * G0);
        o.y = (float)(u1 - lam * G1);
        reinterpret_cast<float2*>(out)[row0 + r] = o;
    }
}

extern "C" void kernel_launch(void* const* d_in, const int* in_sizes, int n_in,
                              void* d_out, int out_size, void* d_ws, size_t ws_size,
                              hipStream_t stream) {
    const float* x   = (const float*)d_in[0];
    const float* W1  = (const float*)d_in[1];
    const float* b1  = (const float*)d_in[2];
    const float* W21 = (const float*)d_in[3];
    const float* b21 = (const float*)d_in[4];
    const float* W22 = (const float*)d_in[5];
    const float* b22 = (const float*)d_in[6];
    const float* W31 = (const float*)d_in[7];
    const float* b31 = (const float*)d_in[8];
    const float* W32 = (const float*)d_in[9];
    const float* b32 = (const float*)d_in[10];
    // d_in[11] = sgn, unused by the reference forward pass.

    float* Wt  = (float*)d_ws;           // 512*256*4 = 512 KiB, rebuilt every call
    float* out = (float*)d_out;

    transpose_w_kernel<<<dim3(512), dim3(256), 0, stream>>>(W21, W22, Wt);
    barriernet_kernel<<<dim3(NBATCH / MT), dim3(NTHREADS), 0, stream>>>(
        x, W1, b1, b21, b22, W31, b31, W32, b32, Wt, out);
}

// Round 13
// 1152.086 us; speedup vs baseline: 3.7798x; 3.7798x over previous
//
#include <hip/hip_runtime.h>
#include <math.h>

// BarrierNet fused kernel, fp32, round 13: fix round-12 accumulator spill.
// Round-12 (WCOLS=64, launch_bounds(256,5)): 4354us, VGPR=48 (<64!), WRITE
// 1.38GB, FETCH 342MB, VALUBusy 13.8% -> acc[64] demoted to scratch; the
// 5-waves/EU cap (96 VGPR) was below the allocator's transient pressure.
// Fix: launch_bounds(256,3) -> ~168 VGPR cap, allocator headroom to promote
// acc[64]+transients; HW occupancy self-sets at ~512/VGPR ~ 5 waves/EU.
// Math unchanged from rounds 10/12 -> bit-identical output (absmax 0.5).
// Sentinels for next round: VGPR must be >=64; WRITE_SIZE ~2MB; FETCH ~6.3MB.
//   block = 256 thr (4 waves), 64 rows (lane=row), wave owns 64 cols of
//   concat(h21,h22); 16 chunks x 32 k.

#define NBATCH 262144
#define MT 64
#define NTHREADS 256
#define WCOLS 64    // cols per wave
#define CHUNK 32
#define NCHUNK 16   // 512 / CHUNK

__global__ void transpose_w_kernel(const float* __restrict__ W21,
                                   const float* __restrict__ W22,
                                   float* __restrict__ Wt) {
    int idx = blockIdx.x * blockDim.x + threadIdx.x;  // 0..131071
    if (idx >= 512 * 256) return;
    int k = idx >> 8;    // 0..511
    int c = idx & 255;   // 0..255
    float v = (c < 128) ? W21[c * 512 + k] : W22[(c - 128) * 512 + k];
    Wt[idx] = v;         // Wt[k][c]
}

__global__ __launch_bounds__(NTHREADS, 3)
void barriernet_kernel(const float* __restrict__ x,
                       const float* __restrict__ W1,  const float* __restrict__ b1,
                       const float* __restrict__ b21, const float* __restrict__ b22,
                       const float* __restrict__ W31, const float* __restrict__ b31,
                       const float* __restrict__ W32, const float* __restrict__ b32,
                       const float* __restrict__ Wt,
                       float* __restrict__ out) {
    __shared__ float red[4][MT][2];      // layer-3 partials per wave (2 KiB)

    const int t    = threadIdx.x;
    const int lane = t & 63;             // = row within block
    const int wv   = __builtin_amdgcn_readfirstlane(t >> 6);  // 0..3 wave-uniform
    const int row0 = blockIdx.x * MT;

    // ---- per-lane raw x (row = lane), one coalesced 16B load ----
    const float4 xi = reinterpret_cast<const float4*>(x)[row0 + lane];
    const float a0 = xi.x, a1 = xi.y, a2 = xi.z, a3 = xi.w;

    // ---- fused recompute-h1 + GEMM over 16 chunks of 32 k ----
    const int cbase = wv * WCOLS;        // wave-uniform col base (0/64/128/192)
    float acc[WCOLS];
    #pragma unroll
    for (int j = 0; j < WCOLS; ++j) acc[j] = 0.f;

    for (int c = 0; c < NCHUNK; ++c) {   // real loop: keep body in I-cache
        #pragma unroll
        for (int kk = 0; kk < CHUNK; ++kk) {
            const int k = c * CHUNK + kk;
            // recompute activation for this k (uniform W1/b1 -> s_load)
            const float* w1k = W1 + k * 4;
            float v = b1[k];
            v = fmaf(a0, w1k[0], v);
            v = fmaf(a1, w1k[1], v);
            v = fmaf(a2, w1k[2], v);
            v = fmaf(a3, w1k[3], v);
            const float act = fmaxf(v, 0.f);
            // 64 FMAs: uniform weight stream, register activation
            const float* wk = Wt + k * 256 + cbase;  // wave-uniform
            #pragma unroll
            for (int j = 0; j < WCOLS; ++j) acc[j] = fmaf(act, wk[j], acc[j]);
        }
    }

    // ---- bias + relu + partial dots with W31/W32 (layer 3) ----
    // wave 0: h21 cols 0-63, wave 1: h21 64-127, wave 2: h22 0-63, wave 3: h22 64-127
    {
        const bool isA  = (wv < 2);
        const int  coff = isA ? (wv * WCOLS) : ((wv - 2) * WCOLS);
        const float* bb = isA ? b21 : b22;
        const float* W3 = isA ? W31 : W32;               // (2,128) row-major
        float q0 = 0.f, q1 = 0.f;
        #pragma unroll
        for (int j = 0; j < WCOLS; ++j) {
            float hv = fmaxf(acc[j] + bb[coff + j], 0.f);
            q0 = fmaf(hv, W3[coff + j], q0);
            q1 = fmaf(hv, W3[128 + coff + j], q1);
        }
        red[wv][lane][0] = q0;
        red[wv][lane][1] = q1;
    }
    __syncthreads();

    // ---- epilogue: CBF-QP closed form (wave 0, one lane per row, fp64) ----
    if (t < MT) {
        const int r = t;                 // lane==row, wave 0 -> own x regs valid
        float x31_0f = b31[0], x31_1f = b31[1];
        float z0f = b32[0], z1f = b32[1];
        x31_0f += red[0][r][0] + red[1][r][0];
        x31_1f += red[0][r][1] + red[1][r][1];
        z0f    += red[2][r][0] + red[3][r][0];
        z1f    += red[2][r][1] + red[3][r][1];

        const double s0 = 4.0 / (1.0 + exp(-(double)z0f));
        const double s1 = 4.0 / (1.0 + exp(-(double)z1f));

        // un-normalize raw x for the physics: STD={10,10,1,2}, MEAN={50,20,0,5}
        const double px = (double)a0 * 10.0 + 50.0;
        const double py = (double)a1 * 10.0 + 20.0;
        const double th = (double)a2;
        const double v  = (double)a3 * 2.0 + 5.0;

        const double st = sin(th), ct = cos(th);
        const double dx = px - 40.0, dy = py - 15.0;
        const double barrier     = dx * dx + dy * dy - 36.0;
        const double barrier_dot = 2.0 * dx * v * ct + 2.0 * dy * v * st;
        const double Lf2b        = 2.0 * v * v;
        const double LgLfbu1     = -2.0 * dx * v * st + 2.0 * dy * v * ct;
        const double LgLfbu2     = 2.0 * dx * ct + 2.0 * dy * st;
        const double G0 = -LgLfbu1, G1 = -LgLfbu2;
        const double h  = Lf2b + (s0 + s1) * barrier_dot + s0 * s1 * barrier;
        const double u0 = -(double)x31_0f, u1 = -(double)x31_1f;
        const double Gu = G0 * u0 + G1 * u1;
        const double gg = fmax(G0 * G0 + G1 * G1, 1e-12);
        const double lam = fmax(0.0, (Gu - h) / gg);
        float2 o;
        o.x = (float)(u0 - lam * G0);
        o.y = (float)(u1 - lam * G1);
        reinterpret_cast<float2*>(out)[row0 + r] = o;
    }
}

extern "C" void kernel_launch(void* const* d_in, const int* in_sizes, int n_in,
                              void* d_out, int out_size, void* d_ws, size_t ws_size,
                              hipStream_t stream) {
    const float* x   = (const float*)d_in[0];
    const float* W1  = (const float*)d_in[1];
    const float* b1  = (const float*)d_in[2];
    const float* W21 = (const float*)d_in[3];
    const float* b21 = (const float*)d_in[4];
    const float* W22 = (const float*)d_in[5];
    const float* b22 = (const float*)d_in[6];
    const float* W31 = (const float*)d_in[7];
    const float* b31 = (const float*)d_in[8];
    const float* W32 = (const float*)d_in[9];
    const float* b32 = (const float*)d_in[10];
    // d_in[11] = sgn, unused by the reference forward pass.

    float* Wt  = (float*)d_ws;           // 512*256*4 = 512 KiB, rebuilt every call
    float* out = (float*)d_out;

    transpose_w_kernel<<<dim3(512), dim3(256), 0, stream>>>(W21, W22, Wt);
    barriernet_kernel<<<dim3(NBATCH / MT), dim3(NTHREADS), 0, stream>>>(
        x, W1, b1, b21, b22, W31, b31, W32, b32, Wt, out);
}

// Round 14
// 1052.921 us; speedup vs baseline: 4.1357x; 1.0942x over previous
//
#include <hip/hip_runtime.h>
#include <math.h>

// BarrierNet fused kernel, fp32, round 14: revert to round-10 structure
// (WCOLS=32, 512thr/8 waves — best verified: 976us, VALUBusy 65%, Occ 57%)
// + packed-fp32 probe in the GEMM inner loop.
// Round-13 lesson: VALU busy-time invariant ~630us across r10/r13 (976*.65 ~
// 1152*.55) -> tile widening only traded occupancy for stalls; WCOLS=64
// strictly worse. Lever (b): cut busy-time itself via v_pk_fma_f32 (2 fp32
// FMA/instr, gfx90a+ lineage). Expressed as float2 ext_vector +
// __builtin_elementwise_fma: compile-safe; if gfx950 lacks/slow-paths it,
// codegen = two v_fma_f32 = round-10 exactly (bounded downside).
// Pair j = cols (2j,2j+1); per-column fma chain order unchanged ->
// bit-identical output (absmax 0.5).
// Sentinels: dur 650-780 => packed real; dur ~950-1000 => not packed.

#define NBATCH 262144
#define MT 64
#define NTHREADS 512
#define WCOLS 32    // cols per wave
#define CHUNK 32
#define NCHUNK 16   // 512 / CHUNK

typedef float v2f __attribute__((ext_vector_type(2)));

__global__ void transpose_w_kernel(const float* __restrict__ W21,
                                   const float* __restrict__ W22,
                                   float* __restrict__ Wt) {
    int idx = blockIdx.x * blockDim.x + threadIdx.x;  // 0..131071
    if (idx >= 512 * 256) return;
    int k = idx >> 8;    // 0..511
    int c = idx & 255;   // 0..255
    float v = (c < 128) ? W21[c * 512 + k] : W22[(c - 128) * 512 + k];
    Wt[idx] = v;         // Wt[k][c]
}

__global__ __launch_bounds__(NTHREADS, 4)
void barriernet_kernel(const float* __restrict__ x,
                       const float* __restrict__ W1,  const float* __restrict__ b1,
                       const float* __restrict__ b21, const float* __restrict__ b22,
                       const float* __restrict__ W31, const float* __restrict__ b31,
                       const float* __restrict__ W32, const float* __restrict__ b32,
                       const float* __restrict__ Wt,
                       float* __restrict__ out) {
    __shared__ float red[8][MT][2];      // layer-3 partials per wave (4 KiB)

    const int t    = threadIdx.x;
    const int lane = t & 63;             // = row within block
    const int wv   = __builtin_amdgcn_readfirstlane(t >> 6);  // 0..7 wave-uniform
    const int row0 = blockIdx.x * MT;

    // ---- per-lane raw x (row = lane), one coalesced 16B load ----
    const float4 xi = reinterpret_cast<const float4*>(x)[row0 + lane];
    const float a0 = xi.x, a1 = xi.y, a2 = xi.z, a3 = xi.w;

    // ---- fused recompute-h1 + GEMM over 16 chunks of 32 k ----
    const int cbase = wv * WCOLS;        // wave-uniform col base
    v2f acc[WCOLS / 2];                  // pair j = cols (2j, 2j+1)
    #pragma unroll
    for (int j = 0; j < WCOLS / 2; ++j) acc[j] = (v2f){0.f, 0.f};

    for (int c = 0; c < NCHUNK; ++c) {   // real loop: keep body in I-cache
        #pragma unroll
        for (int kk = 0; kk < CHUNK; ++kk) {
            const int k = c * CHUNK + kk;
            // recompute activation for this k (uniform W1/b1 -> s_load)
            const float* w1k = W1 + k * 4;
            float v = b1[k];
            v = fmaf(a0, w1k[0], v);
            v = fmaf(a1, w1k[1], v);
            v = fmaf(a2, w1k[2], v);
            v = fmaf(a3, w1k[3], v);
            const float act = fmaxf(v, 0.f);
            const v2f av = {act, act};
            // 16 packed FMAs: uniform weight stream (8B-aligned pairs)
            const v2f* wk = reinterpret_cast<const v2f*>(Wt + k * 256 + cbase);
            #pragma unroll
            for (int j = 0; j < WCOLS / 2; ++j)
                acc[j] = __builtin_elementwise_fma(av, wk[j], acc[j]);
        }
    }

    // ---- bias + relu + partial dots with W31/W32 (layer 3) ----
    // waves 0-3: h21 cols, waves 4-7: h22 cols (as round 10)
    {
        const bool isA  = (wv < 4);
        const int  coff = isA ? cbase : (cbase - 128);   // col within its matrix
        const float* bb = isA ? b21 : b22;
        const float* W3 = isA ? W31 : W32;               // (2,128) row-major
        float q0 = 0.f, q1 = 0.f;
        #pragma unroll
        for (int j = 0; j < WCOLS; ++j) {
            const float accj = (j & 1) ? acc[j >> 1].y : acc[j >> 1].x;
            float hv = fmaxf(accj + bb[coff + j], 0.f);
            q0 = fmaf(hv, W3[coff + j], q0);
            q1 = fmaf(hv, W3[128 + coff + j], q1);
        }
        red[wv][lane][0] = q0;
        red[wv][lane][1] = q1;
    }
    __syncthreads();

    // ---- epilogue: CBF-QP closed form (wave 0, one lane per row, fp64) ----
    if (t < MT) {
        const int r = t;                 // lane==row, wave 0 -> own x regs valid
        float x31_0f = b31[0], x31_1f = b31[1];
        float z0f = b32[0], z1f = b32[1];
        #pragma unroll
        for (int w = 0; w < 4; ++w) { x31_0f += red[w][r][0]; x31_1f += red[w][r][1]; }
        #pragma unroll
        for (int w = 4; w < 8; ++w) { z0f += red[w][r][0]; z1f += red[w][r][1]; }

        const double s0 = 4.0 / (1.0 + exp(-(double)z0f));
        const double s1 = 4.0 / (1.0 + exp(-(double)z1f));

        // un-normalize raw x for the physics: STD={10,10,1,2}, MEAN={50,20,0,5}
        const double px = (double)a0 * 10.0 + 50.0;
        const double py = (double)a1 * 10.0 + 20.0;
        const double th = (double)a2;
        const double v  = (double)a3 * 2.0 + 5.0;

        const double st = sin(th), ct = cos(th);
        const double dx = px - 40.0, dy = py - 15.0;
        const double barrier     = dx * dx + dy * dy - 36.0;
        const double barrier_dot = 2.0 * dx * v * ct + 2.0 * dy * v * st;
        const double Lf2b        = 2.0 * v * v;
        const double LgLfbu1     = -2.0 * dx * v * st + 2.0 * dy * v * ct;
        const double LgLfbu2     = 2.0 * dx * ct + 2.0 * dy * st;
        const double G0 = -LgLfbu1, G1 = -LgLfbu2;
        const double h  = Lf2b + (s0 + s1) * barrier_dot + s0 * s1 * barrier;
        const double u0 = -(double)x31_0f, u1 = -(double)x31_1f;
        const double Gu = G0 * u0 + G1 * u1;
        const double gg = fmax(G0 * G0 + G1 * G1, 1e-12);
        const double lam = fmax(0.0, (Gu - h) / gg);
        float2 o;
        o.x = (float)(u0 - lam * G0);
        o.y = (float)(u1 - lam * G1);
        reinterpret_cast<float2*>(out)[row0 + r] = o;
    }
}

extern "C" void kernel_launch(void* const* d_in, const int* in_sizes, int n_in,
                              void* d_out, int out_size, void* d_ws, size_t ws_size,
                              hipStream_t stream) {
    const float* x   = (const float*)d_in[0];
    const float* W1  = (const float*)d_in[1];
    const float* b1  = (const float*)d_in[2];
    const float* W21 = (const float*)d_in[3];
    const float* b21 = (const float*)d_in[4];
    const float* W22 = (const float*)d_in[5];
    const float* b22 = (const float*)d_in[6];
    const float* W31 = (const float*)d_in[7];
    const float* b31 = (const float*)d_in[8];
    const float* W32 = (const float*)d_in[9];
    const float* b32 = (const float*)d_in[10];
    // d_in[11] = sgn, unused by the reference forward pass.

    float* Wt  = (float*)d_ws;           // 512*256*4 = 512 KiB, rebuilt every call
    float* out = (float*)d_out;

    transpose_w_kernel<<<dim3(512), dim3(256), 0, stream>>>(W21, W22, Wt);
    barriernet_kernel<<<dim3(NBATCH / MT), dim3(NTHREADS), 0, stream>>>(
        x, W1, b1, b21, b22, W31, b31, W32, b32, Wt, out);
}

// Round 15
// 838.842 us; speedup vs baseline: 5.1912x; 1.2552x over previous
//
#include <hip/hip_runtime.h>
#include <math.h>

// BarrierNet fused kernel, fp32, round 15: 2 rows/lane to halve weight-fetch
// pressure. History: r10 (WCOLS=32, 1 row/lane): 976us, busy 634us, stall
// ~340us on the wave-uniform s_load weight stream. r13 (WCOLS=64): worse
// (occupancy trade). r14 (packed fp32): busy unchanged -> no v_pk_fma_f32
// double-rate on CDNA4 (spec: 157.3 TF = unpacked); reverted.
// This round: block = 128 rows, each lane owns rows (lane, 64+lane). Per
// k-step the 128B weight fetch + W1-row fetch feed 64 FMAs + 2 recomputes
// (was 32 + 1): fetch:compute ratio halves -> stall/cycle halves.
// Per-column per-row fma chain order unchanged -> bit-identical (absmax 0.5).
// Spill sentinels (r12 lesson): VGPR must be >=96; WRITE_SIZE ~2MB.
//   block = 512 thr (8 waves), wave owns 32 cols of concat(h21,h22),
//   lane owns 2 rows; 16 chunks x 32 k.

#define NBATCH 262144
#define MT 128      // rows per block (2 per lane)
#define NTHREADS 512
#define WCOLS 32    // cols per wave
#define CHUNK 32
#define NCHUNK 16   // 512 / CHUNK

__global__ void transpose_w_kernel(const float* __restrict__ W21,
                                   const float* __restrict__ W22,
                                   float* __restrict__ Wt) {
    int idx = blockIdx.x * blockDim.x + threadIdx.x;  // 0..131071
    if (idx >= 512 * 256) return;
    int k = idx >> 8;    // 0..511
    int c = idx & 255;   // 0..255
    float v = (c < 128) ? W21[c * 512 + k] : W22[(c - 128) * 512 + k];
    Wt[idx] = v;         // Wt[k][c]
}

__global__ __launch_bounds__(NTHREADS, 3)
void barriernet_kernel(const float* __restrict__ x,
                       const float* __restrict__ W1,  const float* __restrict__ b1,
                       const float* __restrict__ b21, const float* __restrict__ b22,
                       const float* __restrict__ W31, const float* __restrict__ b31,
                       const float* __restrict__ W32, const float* __restrict__ b32,
                       const float* __restrict__ Wt,
                       float* __restrict__ out) {
    __shared__ float red[8][MT][2];      // layer-3 partials per wave (8 KiB)

    const int t    = threadIdx.x;
    const int lane = t & 63;
    const int wv   = __builtin_amdgcn_readfirstlane(t >> 6);  // 0..7 wave-uniform
    const int row0 = blockIdx.x * MT;

    // ---- per-lane raw x for the lane's two rows (coalesced 16B loads) ----
    const float4 xa = reinterpret_cast<const float4*>(x)[row0 + lane];
    const float4 xb = reinterpret_cast<const float4*>(x)[row0 + 64 + lane];

    // ---- fused recompute-h1 + GEMM over 16 chunks of 32 k ----
    const int cbase = wv * WCOLS;        // wave-uniform col base
    float accA[WCOLS], accB[WCOLS];
    #pragma unroll
    for (int j = 0; j < WCOLS; ++j) { accA[j] = 0.f; accB[j] = 0.f; }

    for (int c = 0; c < NCHUNK; ++c) {   // real loop: keep body in I-cache
        #pragma unroll
        for (int kk = 0; kk < CHUNK; ++kk) {
            const int k = c * CHUNK + kk;
            // recompute both rows' activation (shared uniform W1 row fetch)
            const float* w1k = W1 + k * 4;
            const float w0 = w1k[0], w1 = w1k[1], w2 = w1k[2], w3 = w1k[3];
            const float bk = b1[k];
            float va = bk;
            va = fmaf(xa.x, w0, va);
            va = fmaf(xa.y, w1, va);
            va = fmaf(xa.z, w2, va);
            va = fmaf(xa.w, w3, va);
            const float actA = fmaxf(va, 0.f);
            float vb = bk;
            vb = fmaf(xb.x, w0, vb);
            vb = fmaf(xb.y, w1, vb);
            vb = fmaf(xb.z, w2, vb);
            vb = fmaf(xb.w, w3, vb);
            const float actB = fmaxf(vb, 0.f);
            // 64 FMAs per 128B uniform weight fetch (was 32)
            const float* wk = Wt + k * 256 + cbase;  // wave-uniform -> s_load
            #pragma unroll
            for (int j = 0; j < WCOLS; ++j) {
                const float w = wk[j];
                accA[j] = fmaf(actA, w, accA[j]);
                accB[j] = fmaf(actB, w, accB[j]);
            }
        }
    }

    // ---- bias + relu + partial dots with W31/W32 (layer 3), both rows ----
    {
        const bool isA  = (wv < 4);
        const int  coff = isA ? cbase : (cbase - 128);   // col within its matrix
        const float* bb = isA ? b21 : b22;
        const float* W3 = isA ? W31 : W32;               // (2,128) row-major
        float qa0 = 0.f, qa1 = 0.f, qb0 = 0.f, qb1 = 0.f;
        #pragma unroll
        for (int j = 0; j < WCOLS; ++j) {
            const float bj  = bb[coff + j];
            const float w30 = W3[coff + j];
            const float w31 = W3[128 + coff + j];
            const float ha = fmaxf(accA[j] + bj, 0.f);
            qa0 = fmaf(ha, w30, qa0);
            qa1 = fmaf(ha, w31, qa1);
            const float hb = fmaxf(accB[j] + bj, 0.f);
            qb0 = fmaf(hb, w30, qb0);
            qb1 = fmaf(hb, w31, qb1);
        }
        red[wv][lane][0]      = qa0;
        red[wv][lane][1]      = qa1;
        red[wv][64 + lane][0] = qb0;
        red[wv][64 + lane][1] = qb1;
    }
    __syncthreads();

    // ---- epilogue: CBF-QP closed form (wave 0; each lane does its 2 rows, fp64) ----
    if (t < 64) {
        #pragma unroll
        for (int half = 0; half < 2; ++half) {
            const int r = half * 64 + lane;          // row within block
            const float4 xr = half ? xb : xa;        // this thread's own regs
            float x31_0f = b31[0], x31_1f = b31[1];
            float z0f = b32[0], z1f = b32[1];
            #pragma unroll
            for (int w = 0; w < 4; ++w) { x31_0f += red[w][r][0]; x31_1f += red[w][r][1]; }
            #pragma unroll
            for (int w = 4; w < 8; ++w) { z0f += red[w][r][0]; z1f += red[w][r][1]; }

            const double s0 = 4.0 / (1.0 + exp(-(double)z0f));
            const double s1 = 4.0 / (1.0 + exp(-(double)z1f));

            // un-normalize raw x for the physics: STD={10,10,1,2}, MEAN={50,20,0,5}
            const double px = (double)xr.x * 10.0 + 50.0;
            const double py = (double)xr.y * 10.0 + 20.0;
            const double th = (double)xr.z;
            const double v  = (double)xr.w * 2.0 + 5.0;

            const double st = sin(th), ct = cos(th);
            const double dx = px - 40.0, dy = py - 15.0;
            const double barrier     = dx * dx + dy * dy - 36.0;
            const double barrier_dot = 2.0 * dx * v * ct + 2.0 * dy * v * st;
            const double Lf2b        = 2.0 * v * v;
            const double LgLfbu1     = -2.0 * dx * v * st + 2.0 * dy * v * ct;
            const double LgLfbu2     = 2.0 * dx * ct + 2.0 * dy * st;
            const double G0 = -LgLfbu1, G1 = -LgLfbu2;
            const double h  = Lf2b + (s0 + s1) * barrier_dot + s0 * s1 * barrier;
            const double u0 = -(double)x31_0f, u1 = -(double)x31_1f;
            const double Gu = G0 * u0 + G1 * u1;
            const double gg = fmax(G0 * G0 + G1 * G1, 1e-12);
            const double lam = fmax(0.0, (Gu - h) / gg);
            float2 o;
            o.x = (float)(u0 - lam * G0);
            o.y = (float)(u1 - lam * G1);
            reinterpret_cast<float2*>(out)[row0 + r] = o;
        }
    }
}

extern "C" void kernel_launch(void* const* d_in, const int* in_sizes, int n_in,
                              void* d_out, int out_size, void* d_ws, size_t ws_size,
                              hipStream_t stream) {
    const float* x   = (const float*)d_in[0];
    const float* W1  = (const float*)d_in[1];
    const float* b1  = (const float*)d_in[2];
    const float* W21 = (const float*)d_in[3];
    const float* b21 = (const float*)d_in[4];
    const float* W22 = (const float*)d_in[5];
    const float* b22 = (const float*)d_in[6];
    const float* W31 = (const float*)d_in[7];
    const float* b31 = (const float*)d_in[8];
    const float* W32 = (const float*)d_in[9];
    const float* b32 = (const float*)d_in[10];
    // d_in[11] = sgn, unused by the reference forward pass.

    float* Wt  = (float*)d_ws;           // 512*256*4 = 512 KiB, rebuilt every call
    float* out = (float*)d_out;

    transpose_w_kernel<<<dim3(512), dim3(256), 0, stream>>>(W21, W22, Wt);
    barriernet_kernel<<<dim3(NBATCH / MT), dim3(NTHREADS), 0, stream>>>(
        x, W1, b1, b21, b22, W31, b31, W32, b32, Wt, out);
}